// Round 1
// baseline (264.067 us; speedup 1.0000x reference)
//
#include <hip/hip_runtime.h>
#include <stdint.h>

#define B 8
#define NQ 100000
#define NCLS 10
#define NELEM 1000000        // elements per batch (NQ*NCLS)
#define NV4 250000           // float4 per batch
#define KTOP 100
#define NPTS 20
#define BINS 2048
#define CAP 4096
#define BLOCKS_PER_BATCH 32
#define THREADS 256

// Order-preserving monotone key for f32 (larger float <-> larger key)
__device__ __forceinline__ uint32_t fkey(float x) {
  uint32_t u = __float_as_uint(x);
  return (u & 0x80000000u) ? ~u : (u | 0x80000000u);
}

__global__ void hist_kernel(const float* __restrict__ cls, uint32_t* __restrict__ hist) {
  __shared__ uint32_t lh[BINS];
  int b   = blockIdx.x / BLOCKS_PER_BATCH;
  int sub = blockIdx.x % BLOCKS_PER_BATCH;
  for (int i = threadIdx.x; i < BINS; i += THREADS) lh[i] = 0;
  __syncthreads();
  const float4* src = (const float4*)(cls + (size_t)b * NELEM);
  for (int i = sub * THREADS + threadIdx.x; i < NV4; i += BLOCKS_PER_BATCH * THREADS) {
    float4 v = src[i];
    atomicAdd(&lh[fkey(v.x) >> 21], 1u);
    atomicAdd(&lh[fkey(v.y) >> 21], 1u);
    atomicAdd(&lh[fkey(v.z) >> 21], 1u);
    atomicAdd(&lh[fkey(v.w) >> 21], 1u);
  }
  __syncthreads();
  uint32_t* gh = hist + (size_t)b * BINS;
  for (int i = threadIdx.x; i < BINS; i += THREADS)
    if (lh[i]) atomicAdd(&gh[i], lh[i]);
}

__global__ void collect_kernel(const float* __restrict__ cls,
                               const uint32_t* __restrict__ hist,
                               uint32_t* __restrict__ candCount,
                               uint64_t* __restrict__ cand) {
  __shared__ uint32_t lh[BINS];
  __shared__ uint32_t s_b1;
  int b   = blockIdx.x / BLOCKS_PER_BATCH;
  int sub = blockIdx.x % BLOCKS_PER_BATCH;
  const uint32_t* gh = hist + (size_t)b * BINS;
  for (int i = threadIdx.x; i < BINS; i += THREADS) lh[i] = gh[i];
  __syncthreads();
  if (threadIdx.x == 0) {
    uint32_t cum = 0;
    int bin = BINS - 1;
    for (; bin >= 0; --bin) { cum += lh[bin]; if (cum >= KTOP) break; }
    s_b1 = (uint32_t)(bin < 0 ? 0 : bin);
  }
  __syncthreads();
  uint32_t b1 = s_b1;
  const float4* src = (const float4*)(cls + (size_t)b * NELEM);
  for (int i = sub * THREADS + threadIdx.x; i < NV4; i += BLOCKS_PER_BATCH * THREADS) {
    float4 v = src[i];
    float xs[4] = {v.x, v.y, v.z, v.w};
#pragma unroll
    for (int l = 0; l < 4; ++l) {
      uint32_t key = fkey(xs[l]);
      if ((key >> 21) >= b1) {
        uint32_t slot = atomicAdd(&candCount[b], 1u);
        if (slot < CAP) {
          float s = 1.0f / (1.0f + expf(-xs[l]));
          uint32_t idx = (uint32_t)(4 * i + l);
          // composite sorts desc by sigmoid f32 bits, then asc by index
          cand[(size_t)b * CAP + slot] =
              ((uint64_t)__float_as_uint(s) << 32) | (uint64_t)(0xFFFFFFFFu - idx);
        }
      }
    }
  }
}

__global__ void final_kernel(const float* __restrict__ bbox,
                             const float* __restrict__ pts,
                             const uint32_t* __restrict__ candCount,
                             const uint64_t* __restrict__ cand,
                             float* __restrict__ out) {
  __shared__ uint64_t s[CAP];
  int b = blockIdx.x;
  int tid = threadIdx.x;
  uint32_t cnt = candCount[b];
  if (cnt > CAP) cnt = CAP;
  uint32_t n = 256;
  while (n < cnt) n <<= 1;
  for (uint32_t i = tid; i < n; i += THREADS)
    s[i] = (i < cnt) ? cand[(size_t)b * CAP + i] : 0ull;
  __syncthreads();
  // bitonic sort, descending
  for (uint32_t k = 2; k <= n; k <<= 1) {
    for (uint32_t j = k >> 1; j > 0; j >>= 1) {
      for (uint32_t i = tid; i < n; i += THREADS) {
        uint32_t ixj = i ^ j;
        if (ixj > i) {
          uint64_t a = s[i], c = s[ixj];
          bool desc = ((i & k) == 0);
          if (desc ? (a < c) : (a > c)) { s[i] = c; s[ixj] = a; }
        }
      }
      __syncthreads();
    }
  }
  // threshold-decay mask logic (scalar, replicated per thread)
  float smax = __uint_as_float((uint32_t)(s[0] >> 32));
  int mode;       // 0: score > thr ; 1: score >= thr ; 2: all true
  float thr = 0.1f;
  if (smax > 0.1f) {
    mode = 0;
  } else {
    float tmp = 0.1f;
    mode = 2;
    while (true) {
      tmp *= 0.9f;
      if (tmp < 0.01f) { mode = 2; break; }
      if (smax >= tmp) { mode = 1; thr = tmp; break; }
    }
  }
  if (tid < KTOP) {
    uint64_t comp = s[tid];
    uint32_t sbits = (uint32_t)(comp >> 32);
    float score = __uint_as_float(sbits);
    uint32_t idx = 0xFFFFFFFFu - (uint32_t)(comp & 0xFFFFFFFFu);
    uint32_t label = idx % NCLS;
    uint32_t bidx = idx / NCLS;
    if (bidx >= NQ) bidx = 0;  // safety (unreachable for valid data)
    float4 bb = ((const float4*)(bbox + (size_t)b * NQ * 4))[bidx];
    // cxcywh -> xyxy, scale [30,60,30,60], off [-15,-30,-15,-30]; avoid FMA contraction
    float hx = __fmul_rn(bb.z, 0.5f);
    float hy = __fmul_rn(bb.w, 0.5f);
    float x1 = __fadd_rn(__fmul_rn(__fsub_rn(bb.x, hx), 30.0f), -15.0f);
    float y1 = __fadd_rn(__fmul_rn(__fsub_rn(bb.y, hy), 60.0f), -30.0f);
    float x2 = __fadd_rn(__fmul_rn(__fadd_rn(bb.x, hx), 30.0f), -15.0f);
    float y2 = __fadd_rn(__fmul_rn(__fadd_rn(bb.y, hy), 60.0f), -30.0f);
    bool rmask = (x1 >= -20.0f) & (y1 >= -35.0f) & (x2 >= -20.0f) & (y2 >= -35.0f) &
                 (x1 <= 20.0f) & (y1 <= 35.0f) & (x2 <= 20.0f) & (y2 <= 35.0f);
    bool tmask = (mode == 2) || (mode == 0 ? (score > thr) : (score >= thr));
    bool mask = rmask && tmask;

    float* oBoxes  = out;                        // [B][K][4]
    float* oScores = out + B * KTOP * 4;         // [B][K]
    float* oLabels = oScores + B * KTOP;         // [B][K]
    float* oPts    = oLabels + B * KTOP;         // [B][K][NPTS][2]
    float* oMask   = oPts + B * KTOP * NPTS * 2; // [B][K]
    size_t rb = (size_t)b * KTOP + (size_t)tid;

    float4 obx = mask ? make_float4(x1, y1, x2, y2) : make_float4(0.f, 0.f, 0.f, 0.f);
    ((float4*)oBoxes)[rb] = obx;
    oScores[rb] = mask ? score : 0.0f;
    oLabels[rb] = mask ? (float)label : 0.0f;
    oMask[rb] = mask ? 1.0f : 0.0f;

    const float2* ps = (const float2*)(pts + (size_t)b * NQ * NPTS * 2) + (size_t)bidx * NPTS;
    float2* po = (float2*)oPts + rb * NPTS;
#pragma unroll
    for (int j = 0; j < NPTS; ++j) {
      float2 p = ps[j];
      float px = __fadd_rn(__fmul_rn(p.x, 30.0f), -15.0f);
      float py = __fadd_rn(__fmul_rn(p.y, 60.0f), -30.0f);
      po[j] = mask ? make_float2(px, py) : make_float2(0.0f, 0.0f);
    }
  }
}

extern "C" void kernel_launch(void* const* d_in, const int* in_sizes, int n_in,
                              void* d_out, int out_size, void* d_ws, size_t ws_size,
                              hipStream_t stream) {
  const float* cls  = (const float*)d_in[0];
  const float* bbox = (const float*)d_in[1];
  const float* pts  = (const float*)d_in[2];
  float* out = (float*)d_out;

  uint8_t* ws = (uint8_t*)d_ws;
  uint32_t* hist      = (uint32_t*)ws;                        // B*BINS u32  = 64 KiB
  uint32_t* candCount = (uint32_t*)(ws + B * BINS * 4);       // B u32
  uint64_t* cand      = (uint64_t*)(ws + B * BINS * 4 + 256); // B*CAP u64 = 256 KiB

  hipMemsetAsync(d_ws, 0, B * BINS * 4 + 256, stream);
  hist_kernel<<<B * BLOCKS_PER_BATCH, THREADS, 0, stream>>>(cls, hist);
  collect_kernel<<<B * BLOCKS_PER_BATCH, THREADS, 0, stream>>>(cls, hist, candCount, cand);
  final_kernel<<<B, THREADS, 0, stream>>>(bbox, pts, candCount, cand, out);
}